// Round 1
// baseline (94.437 us; speedup 1.0000x reference)
//
#include <hip/hip_runtime.h>
#include <cstdint>

#define BLOCK 256

__device__ __forceinline__ float fast_elu(float x) {
    // jax.nn.elu: x>0 ? x : expm1(x)
    return x > 0.0f ? x : __expf(x) - 1.0f;
}

__device__ __forceinline__ float fast_softplus(float x) {
    // numerically stable: max(x,0) + log1p(exp(-|x|))
    return fmaxf(x, 0.0f) + __logf(1.0f + __expf(-fabsf(x)));
}

__global__ void __launch_bounds__(BLOCK)
od_kernel(const float* __restrict__ t_p,
          const float* __restrict__ comp,
          const float* __restrict__ null_lw,
          const float* __restrict__ null_iw,
          const float* __restrict__ W1, const float* __restrict__ b1,
          const float* __restrict__ W2, const float* __restrict__ b2,
          const float* __restrict__ W3, const float* __restrict__ b3,
          const float* __restrict__ W_lw, const float* __restrict__ b_lw,
          const float* __restrict__ W_iw, const float* __restrict__ b_iw,
          float* __restrict__ out, int B)
{
    constexpr int GAS[76] = {
        0,0,0,0,0,0,0,0,0,0,0,0,0,0,0,0,0,0,0,0,0,0,0,0,0,0,0,0,0,
        1,1,1,1,1,1,1,1,1,1,1,1,1,
        2,2,2,2,2,2,2,2,2,
        3,3,3,
        4,4,4,4,4,4,4,4,4,
        5,5,5,5,5,5,5,5,5,5,5,5,5};
    constexpr int CHAN[76] = {
        0,1,2,3,4,5,6,7,8,9,10,11,12,13,14,15,16,17,18,19,20,21,22,23,24,25,26,27,28,
        0,1,2,17,18,19,20,21,22,25,26,27,28,
        0,1,2,5,6,9,10,13,14,
        0,1,2,
        0,1,2,3,4,7,8,11,12,
        0,1,2,15,16,17,18,19,20,21,22,27,28};

    // per-wave staging buffer: 64 rows x 29 channels (7424 B per wave)
    __shared__ float stage[BLOCK / 64][64 * 29];

    const int tid  = blockIdx.x * BLOCK + threadIdx.x;
    const int wave = threadIdx.x >> 6;
    const int lane = threadIdx.x & 63;
    const int row  = tid < B ? tid : B - 1;   // clamp; stores are guarded below

    // vectorized per-row input loads
    const float2 tp = *reinterpret_cast<const float2*>(t_p + (size_t)row * 2);
    const float4 ca = *reinterpret_cast<const float4*>(comp + (size_t)row * 8);
    const float4 cb = *reinterpret_cast<const float4*>(comp + (size_t)row * 8 + 4);
    const float cg[6] = {ca.x, ca.y, ca.z, ca.w, cb.x, cb.y};
    const float c6 = cb.z, c7 = cb.w;
    const float nl = null_lw[row];
    const float ni = null_iw[row];

    float tau[29];
    #pragma unroll
    for (int i = 0; i < 29; ++i) tau[i] = 0.0f;

    // 76 tiny MLPs, fully unrolled so CHAN/GAS indices are compile-time and
    // weight addresses are uniform (scalar s_load path, operands in SGPRs).
    #pragma unroll
    for (int n = 0; n < 76; ++n) {
        float h1[4];
        #pragma unroll
        for (int o = 0; o < 4; ++o)
            h1[o] = fast_elu(fmaf(tp.x, W1[n * 8 + o],
                             fmaf(tp.y, W1[n * 8 + 4 + o], b1[n * 4 + o])));
        float h2[4];
        #pragma unroll
        for (int o = 0; o < 4; ++o) {
            float a = b2[n * 4 + o];
            #pragma unroll
            for (int i = 0; i < 4; ++i)
                a = fmaf(h1[i], W2[n * 16 + i * 4 + o], a);
            h2[o] = fast_elu(a);
        }
        float a = b3[n];
        #pragma unroll
        for (int i = 0; i < 4; ++i)
            a = fmaf(h2[i], W3[n * 4 + i], a);
        const float ke = fast_softplus(a);
        tau[CHAN[n]] = fmaf(ke, cg[GAS[n]], tau[CHAN[n]]);
    }

    const size_t BN = (size_t)B * 29;
    const int wave_base = blockIdx.x * BLOCK + wave * 64;  // first row of this wave
    const long long rem = (long long)B - wave_base;        // valid rows for this wave
    float* wstage = stage[wave];

    // ---- output 0: tau_gases ----
    // stage [lane][ch] (stride 29, coprime with 32 banks -> conflict-free),
    // then write stride-1 coalesced. Per-wave buffer: no barrier needed.
    #pragma unroll
    for (int i = 0; i < 29; ++i) wstage[lane * 29 + i] = tau[i];
    {
        float* dst = out + (size_t)wave_base * 29;
        if (rem >= 64) {
            #pragma unroll
            for (int i = 0; i < 29; ++i) dst[i * 64 + lane] = wstage[i * 64 + lane];
        } else if (rem > 0) {
            const int lim = (int)rem * 29;
            for (int i = 0; i < 29; ++i) {
                const int idx = i * 64 + lane;
                if (idx < lim) dst[idx] = wstage[idx];
            }
        }
    }

    // ---- output 1: tau_lw ----
    #pragma unroll
    for (int i = 0; i < 29; ++i)
        wstage[lane * 29 + i] = fast_softplus(fmaf(nl, W_lw[i], b_lw[i])) * c6;
    {
        float* dst = out + BN + (size_t)wave_base * 29;
        if (rem >= 64) {
            #pragma unroll
            for (int i = 0; i < 29; ++i) dst[i * 64 + lane] = wstage[i * 64 + lane];
        } else if (rem > 0) {
            const int lim = (int)rem * 29;
            for (int i = 0; i < 29; ++i) {
                const int idx = i * 64 + lane;
                if (idx < lim) dst[idx] = wstage[idx];
            }
        }
    }

    // ---- output 2: tau_iw ----
    #pragma unroll
    for (int i = 0; i < 29; ++i)
        wstage[lane * 29 + i] = fast_softplus(fmaf(ni, W_iw[i], b_iw[i])) * c7;
    {
        float* dst = out + 2 * BN + (size_t)wave_base * 29;
        if (rem >= 64) {
            #pragma unroll
            for (int i = 0; i < 29; ++i) dst[i * 64 + lane] = wstage[i * 64 + lane];
        } else if (rem > 0) {
            const int lim = (int)rem * 29;
            for (int i = 0; i < 29; ++i) {
                const int idx = i * 64 + lane;
                if (idx < lim) dst[idx] = wstage[idx];
            }
        }
    }
}

extern "C" void kernel_launch(void* const* d_in, const int* in_sizes, int n_in,
                              void* d_out, int out_size, void* d_ws, size_t ws_size,
                              hipStream_t stream) {
    const float* t_p     = (const float*)d_in[0];
    const float* comp    = (const float*)d_in[1];
    const float* null_lw = (const float*)d_in[2];
    const float* null_iw = (const float*)d_in[3];
    const float* W1      = (const float*)d_in[4];
    const float* b1      = (const float*)d_in[5];
    const float* W2      = (const float*)d_in[6];
    const float* b2      = (const float*)d_in[7];
    const float* W3      = (const float*)d_in[8];
    const float* b3      = (const float*)d_in[9];
    const float* W_lw    = (const float*)d_in[10];
    const float* b_lw    = (const float*)d_in[11];
    const float* W_iw    = (const float*)d_in[12];
    const float* b_iw    = (const float*)d_in[13];
    float* out = (float*)d_out;

    const int B = in_sizes[0] / 2;
    const int blocks = (B + BLOCK - 1) / BLOCK;
    od_kernel<<<blocks, BLOCK, 0, stream>>>(t_p, comp, null_lw, null_iw,
                                            W1, b1, W2, b2, W3, b3,
                                            W_lw, b_lw, W_iw, b_iw, out, B);
}

// Round 2
// 68.545 us; speedup vs baseline: 1.3777x; 1.3777x over previous
//
#include <hip/hip_runtime.h>
#include <cstdint>

#define BLOCK 256
#define ROWS 64   // rows per block (one per lane of a wave)

__device__ __forceinline__ float fast_elu(float x) {
    // jax.nn.elu: x>0 ? x : expm1(x)
    return x > 0.0f ? x : __expf(x) - 1.0f;
}

__device__ __forceinline__ float fast_softplus(float x) {
    // numerically stable: max(x,0) + log1p(exp(-|x|))
    return fmaxf(x, 0.0f) + __logf(1.0f + __expf(-fabsf(x)));
}

__constant__ int dummy_unused;  // keep file self-contained

constexpr int GAS_[76] = {
    0,0,0,0,0,0,0,0,0,0,0,0,0,0,0,0,0,0,0,0,0,0,0,0,0,0,0,0,0,
    1,1,1,1,1,1,1,1,1,1,1,1,1,
    2,2,2,2,2,2,2,2,2,
    3,3,3,
    4,4,4,4,4,4,4,4,4,
    5,5,5,5,5,5,5,5,5,5,5,5,5};
constexpr int CHAN_[76] = {
    0,1,2,3,4,5,6,7,8,9,10,11,12,13,14,15,16,17,18,19,20,21,22,23,24,25,26,27,28,
    0,1,2,17,18,19,20,21,22,25,26,27,28,
    0,1,2,5,6,9,10,13,14,
    0,1,2,
    0,1,2,3,4,7,8,11,12,
    0,1,2,15,16,17,18,19,20,21,22,27,28};

// Run nets [NS, NE): compile-time range so CHAN_/GAS_ indices are constexpr
// (tau stays in registers) and weight addresses are wave-uniform s_loads.
template<int NS, int NE>
__device__ __forceinline__ void run_nets(
    const float* __restrict__ W1, const float* __restrict__ b1,
    const float* __restrict__ W2, const float* __restrict__ b2,
    const float* __restrict__ W3, const float* __restrict__ b3,
    float tpx, float tpy, const float* cg, float* tau)
{
    #pragma unroll
    for (int n = NS; n < NE; ++n) {
        float h1[4];
        #pragma unroll
        for (int o = 0; o < 4; ++o)
            h1[o] = fast_elu(fmaf(tpx, W1[n * 8 + o],
                             fmaf(tpy, W1[n * 8 + 4 + o], b1[n * 4 + o])));
        float h2[4];
        #pragma unroll
        for (int o = 0; o < 4; ++o) {
            float a = b2[n * 4 + o];
            #pragma unroll
            for (int i = 0; i < 4; ++i)
                a = fmaf(h1[i], W2[n * 16 + i * 4 + o], a);
            h2[o] = fast_elu(a);
        }
        float a = b3[n];
        #pragma unroll
        for (int i = 0; i < 4; ++i)
            a = fmaf(h2[i], W3[n * 4 + i], a);
        tau[CHAN_[n]] = fmaf(fast_softplus(a), cg[GAS_[n]], tau[CHAN_[n]]);
    }
}

__global__ void __launch_bounds__(BLOCK)
od_kernel(const float* __restrict__ t_p,
          const float* __restrict__ comp,
          const float* __restrict__ null_lw,
          const float* __restrict__ null_iw,
          const float* __restrict__ W1, const float* __restrict__ b1,
          const float* __restrict__ W2, const float* __restrict__ b2,
          const float* __restrict__ W3, const float* __restrict__ b3,
          const float* __restrict__ W_lw, const float* __restrict__ b_lw,
          const float* __restrict__ W_iw, const float* __restrict__ b_iw,
          float* __restrict__ out, int B)
{
    // 4 partial tau panels: [wave][row][29]; stride 29 coprime w/ 32 banks.
    __shared__ float stage[4][ROWS * 29];

    const int wave = threadIdx.x >> 6;
    const int lane = threadIdx.x & 63;
    const int base = blockIdx.x * ROWS;
    const int row  = (base + lane < B) ? (base + lane) : (B - 1);  // clamped load idx

    const float2 tp = *reinterpret_cast<const float2*>(t_p + (size_t)row * 2);
    const float4 ca = *reinterpret_cast<const float4*>(comp + (size_t)row * 8);
    const float2 cbl = *reinterpret_cast<const float2*>(comp + (size_t)row * 8 + 4);
    const float cg[6] = {ca.x, ca.y, ca.z, ca.w, cbl.x, cbl.y};

    float tau[29];
    #pragma unroll
    for (int i = 0; i < 29; ++i) tau[i] = 0.0f;

    // each wave computes a compile-time quarter of the 76 nets for its 64 rows
    switch (wave) {
        case 0: run_nets< 0, 19>(W1, b1, W2, b2, W3, b3, tp.x, tp.y, cg, tau); break;
        case 1: run_nets<19, 38>(W1, b1, W2, b2, W3, b3, tp.x, tp.y, cg, tau); break;
        case 2: run_nets<38, 57>(W1, b1, W2, b2, W3, b3, tp.x, tp.y, cg, tau); break;
        default: run_nets<57, 76>(W1, b1, W2, b2, W3, b3, tp.x, tp.y, cg, tau); break;
    }

    #pragma unroll
    for (int i = 0; i < 29; ++i) stage[wave][lane * 29 + i] = tau[i];
    __syncthreads();

    const int rem = (B - base < ROWS) ? (B - base) : ROWS;   // valid rows this block
    const int lim = rem * 29;
    const size_t obase = (size_t)base * 29;
    const size_t BN = (size_t)B * 29;

    // ---- output 0: tau_gases = sum of the 4 wave partials; flat coalesced ----
    for (int idx = threadIdx.x; idx < lim; idx += BLOCK) {
        float s = stage[0][idx] + stage[1][idx] + stage[2][idx] + stage[3][idx];
        out[obase + idx] = s;
    }

    // ---- outputs 1,2: lw / iw (no cross-wave dependence; direct coalesced) ----
    for (int idx = threadIdx.x; idx < lim; idx += BLOCK) {
        const int r  = idx / 29;          // magic-mul div
        const int ch = idx - r * 29;
        const int grow = base + r;
        const float nl = null_lw[grow];
        const float ni = null_iw[grow];
        const float c6 = comp[(size_t)grow * 8 + 6];
        const float c7 = comp[(size_t)grow * 8 + 7];
        out[BN + obase + idx]     = fast_softplus(fmaf(nl, W_lw[ch], b_lw[ch])) * c6;
        out[2 * BN + obase + idx] = fast_softplus(fmaf(ni, W_iw[ch], b_iw[ch])) * c7;
    }
}

extern "C" void kernel_launch(void* const* d_in, const int* in_sizes, int n_in,
                              void* d_out, int out_size, void* d_ws, size_t ws_size,
                              hipStream_t stream) {
    const float* t_p     = (const float*)d_in[0];
    const float* comp    = (const float*)d_in[1];
    const float* null_lw = (const float*)d_in[2];
    const float* null_iw = (const float*)d_in[3];
    const float* W1      = (const float*)d_in[4];
    const float* b1      = (const float*)d_in[5];
    const float* W2      = (const float*)d_in[6];
    const float* b2      = (const float*)d_in[7];
    const float* W3      = (const float*)d_in[8];
    const float* b3      = (const float*)d_in[9];
    const float* W_lw    = (const float*)d_in[10];
    const float* b_lw    = (const float*)d_in[11];
    const float* W_iw    = (const float*)d_in[12];
    const float* b_iw    = (const float*)d_in[13];
    float* out = (float*)d_out;

    const int B = in_sizes[0] / 2;
    const int blocks = (B + ROWS - 1) / ROWS;
    od_kernel<<<blocks, BLOCK, 0, stream>>>(t_p, comp, null_lw, null_iw,
                                            W1, b1, W2, b2, W3, b3,
                                            W_lw, b_lw, W_iw, b_iw, out, B);
}